// Round 5
// baseline (226.432 us; speedup 1.0000x reference)
//
#include <hip/hip_runtime.h>

#define N_NODES  10000
#define C_DIM    128
#define H_DIM    8
#define YZ_TOTAL (N_NODES * H_DIM)
#define REP_YZ   32
#define REP_EDGE 10

// Runtime-zero, data-dependent, compiler-opaque (serializes reps; no DCE).
__device__ __forceinline__ int launder_zero(float v) {
    int t = __float_as_int(v);
    int z;
    asm volatile("v_and_b32 %0, 0, %1" : "=v"(z) : "v"(t));
    return z;
}

// ---- K1: exact R4 structure (32 thr/node), core repeated REP_YZ times ----
__global__ void __launch_bounds__(256)
precompute_yz(const float* __restrict__ x, const float* __restrict__ W,
              const float* __restrict__ b, float* __restrict__ yz) {
    const int t = blockIdx.x * blockDim.x + threadIdx.x;
    const int n = t >> 5;
    if (n >= N_NODES) return;
    const int w  = t & 31;
    const int s  = w >> 2;
    const int hp = w & 3;
    const int h0 = hp * 2;
    const int k0 = s * 16;

    int off = 0;
    float ar0 = 0.f, ar1 = 0.f, ac0 = 0.f, ac1 = 0.f;
    for (int rep = 0; rep < REP_YZ; ++rep) {
        const float4* xr4 = (const float4*)(x + (size_t)n * C_DIM) + s * 4 + off;
        float4 xv0 = xr4[0], xv1 = xr4[1], xv2 = xr4[2], xv3 = xr4[3];
        const float xk[16] = { xv0.x,xv0.y,xv0.z,xv0.w, xv1.x,xv1.y,xv1.z,xv1.w,
                               xv2.x,xv2.y,xv2.z,xv2.w, xv3.x,xv3.y,xv3.z,xv3.w };
        const float* wr = W + (size_t)k0 * H_DIM + h0 + off;
        const float* wc = W + (size_t)(C_DIM + k0) * H_DIM + h0 + off;
        ar0 = 0.f; ar1 = 0.f; ac0 = 0.f; ac1 = 0.f;
#pragma unroll
        for (int j = 0; j < 16; ++j) {
            float2 wr2 = *(const float2*)(wr + j * H_DIM);
            float2 wc2 = *(const float2*)(wc + j * H_DIM);
            ar0 = fmaf(xk[j], wr2.x, ar0);
            ar1 = fmaf(xk[j], wr2.y, ar1);
            ac0 = fmaf(xk[j], wc2.x, ac0);
            ac1 = fmaf(xk[j], wc2.y, ac1);
        }
#pragma unroll
        for (int m = 4; m <= 16; m <<= 1) {
            ar0 += __shfl_xor(ar0, m, 64);
            ar1 += __shfl_xor(ar1, m, 64);
            ac0 += __shfl_xor(ac0, m, 64);
            ac1 += __shfl_xor(ac1, m, 64);
        }
        off = launder_zero(ar0) | launder_zero(ac0);   // always 0, opaque
    }

    if (s == 0) {
        float2 bb = *(const float2*)(b + h0);
        *(float2*)(yz + (size_t)n * H_DIM + h0) = make_float2(ar0 + bb.x, ar1 + bb.y);
        *(float2*)(yz + YZ_TOTAL + (size_t)n * H_DIM + h0) = make_float2(ac0, ac1);
    }
}

// ---- K2: exact R4 structure (1 thr/edge), core repeated REP_EDGE times ----
__global__ void edge_alpha(const int* __restrict__ ei,
                           const float* __restrict__ ea,
                           const float* __restrict__ yz,
                           float* __restrict__ out, int E) {
    const int e = blockIdx.x * blockDim.x + threadIdx.x;
    if (e >= E) return;

    int off = 0;
    int r = 0, c = 0;
    float res[8];
    for (int rep = 0; rep < REP_EDGE; ++rep) {
        r = ei[e + off];
        c = ei[E + e + off];
        float a = ea[e + off];
        const float4* yp = (const float4*)(yz + (size_t)r * H_DIM);
        const float4* zp = (const float4*)(yz + YZ_TOTAL + (size_t)c * H_DIM);
        float4 y0 = yp[0], y1 = yp[1];
        float4 z0 = zp[0], z1 = zp[1];
        float v[8] = { y0.x + z0.x, y0.y + z0.y, y0.z + z0.z, y0.w + z0.w,
                       y1.x + z1.x, y1.y + z1.y, y1.z + z1.z, y1.w + z1.w };
        const bool self = (r == c);
        float live = 0.f;
#pragma unroll
        for (int h = 0; h < 8; ++h) {
            float sg = 1.f / (1.f + __expf(-v[h]));
            res[h] = self ? 1.f : sg * a;
            live += res[h];
        }
        off = launder_zero(live);                      // always 0, opaque
    }

    float4* op = (float4*)(out + (size_t)e * H_DIM);
    op[0] = make_float4(res[0], res[1], res[2], res[3]);
    op[1] = make_float4(res[4], res[5], res[6], res[7]);
    out[(size_t)E * H_DIM + e]     = (float)r;
    out[(size_t)E * H_DIM + E + e] = (float)c;
}

extern "C" void kernel_launch(void* const* d_in, const int* in_sizes, int n_in,
                              void* d_out, int out_size, void* d_ws, size_t ws_size,
                              hipStream_t stream) {
    const float* x  = (const float*)d_in[0];
    const int*   ei = (const int*)d_in[1];   // int32 on device per harness convention
    const float* ea = (const float*)d_in[2];
    const float* W  = (const float*)d_in[3];
    const float* b  = (const float*)d_in[4];
    float* out = (float*)d_out;
    float* yz  = (float*)d_ws;               // 2*N*H*4 = 640 KB
    const int E = in_sizes[2];               // 640000

    {
        const int total_threads = N_NODES * 32;                  // 320000
        const int grid = (total_threads + 255) / 256;            // 1250
        hipLaunchKernelGGL(precompute_yz, dim3(grid), dim3(256), 0, stream,
                           x, W, b, yz);
    }
    {
        const int grid = (E + 255) / 256;                        // 2500
        hipLaunchKernelGGL(edge_alpha, dim3(grid), dim3(256), 0, stream,
                           ei, ea, yz, out, E);
    }
}

// Round 7
// 29.438 us; speedup vs baseline: 7.6918x; 7.6918x over previous
//
#include <hip/hip_runtime.h>

#define N_NODES  10000
#define C_DIM    128
#define H_DIM    8
#define YZ_TOTAL (N_NODES * H_DIM)

// clang-native vector types (required by __builtin_nontemporal_store)
typedef float  fx2 __attribute__((ext_vector_type(2)));
typedef float  fx4 __attribute__((ext_vector_type(4)));

// ---------------------------------------------------------------------------
// K1: unchanged from R4 (25.35 us config). 32 threads/node, k-split butterfly.
// ---------------------------------------------------------------------------
__global__ void __launch_bounds__(256)
precompute_yz(const float* __restrict__ x, const float* __restrict__ W,
              const float* __restrict__ b, float* __restrict__ yz) {
    const int t = blockIdx.x * blockDim.x + threadIdx.x;
    const int n = t >> 5;
    if (n >= N_NODES) return;
    const int w  = t & 31;
    const int s  = w >> 2;
    const int hp = w & 3;
    const int h0 = hp * 2;

    const float4* xr4 = (const float4*)(x + (size_t)n * C_DIM) + s * 4;
    float4 xv0 = xr4[0], xv1 = xr4[1], xv2 = xr4[2], xv3 = xr4[3];
    const float xk[16] = { xv0.x,xv0.y,xv0.z,xv0.w, xv1.x,xv1.y,xv1.z,xv1.w,
                           xv2.x,xv2.y,xv2.z,xv2.w, xv3.x,xv3.y,xv3.z,xv3.w };

    const int k0 = s * 16;
    const float* wr = W + (size_t)k0 * H_DIM + h0;
    const float* wc = W + (size_t)(C_DIM + k0) * H_DIM + h0;

    float ar0 = 0.f, ar1 = 0.f, ac0 = 0.f, ac1 = 0.f;
#pragma unroll
    for (int j = 0; j < 16; ++j) {
        float2 wr2 = *(const float2*)(wr + j * H_DIM);
        float2 wc2 = *(const float2*)(wc + j * H_DIM);
        ar0 = fmaf(xk[j], wr2.x, ar0);
        ar1 = fmaf(xk[j], wr2.y, ar1);
        ac0 = fmaf(xk[j], wc2.x, ac0);
        ac1 = fmaf(xk[j], wc2.y, ac1);
    }
#pragma unroll
    for (int m = 4; m <= 16; m <<= 1) {
        ar0 += __shfl_xor(ar0, m, 64);
        ar1 += __shfl_xor(ar1, m, 64);
        ac0 += __shfl_xor(ac0, m, 64);
        ac1 += __shfl_xor(ac1, m, 64);
    }
    if (s == 0) {
        float2 bb = *(const float2*)(b + h0);
        *(float2*)(yz + (size_t)n * H_DIM + h0) = make_float2(ar0 + bb.x, ar1 + bb.y);
        *(float2*)(yz + YZ_TOTAL + (size_t)n * H_DIM + h0) = make_float2(ac0, ac1);
    }
}

// ---------------------------------------------------------------------------
// K2: 2 edges/thread, paired int2/float2 streams, v_rcp sigmoid, NT stores.
// ---------------------------------------------------------------------------
__device__ __forceinline__ float sigmoid_fast(float v) {
    return __builtin_amdgcn_rcpf(1.f + __expf(-v));   // rcp: absmax-safe (R1 precedent)
}

__device__ __forceinline__ void nt_store2(float* p, float a, float b) {
    fx2 v = { a, b };
    __builtin_nontemporal_store(v, (fx2*)p);
}
__device__ __forceinline__ void nt_store4(float* p, float a, float b, float c, float d) {
    fx4 v = { a, b, c, d };
    __builtin_nontemporal_store(v, (fx4*)p);
}

__global__ void __launch_bounds__(256)
edge_alpha(const int* __restrict__ ei, const float* __restrict__ ea,
           const float* __restrict__ yz, float* __restrict__ out, int E) {
    const int t = blockIdx.x * blockDim.x + threadIdx.x;
    const int e = 2 * t;
    if (e >= E) return;
    const size_t ib = (size_t)E * H_DIM;

    if (e + 1 < E) {
        // paired stream loads (adjacent in both ei rows and in ea)
        int2   rp = *(const int2*)(ei + e);
        int2   cp = *(const int2*)(ei + E + e);
        float2 ap = *(const float2*)(ea + e);

        // issue all 4 gathers before any arithmetic
        const float4* yp0 = (const float4*)(yz + (size_t)rp.x * H_DIM);
        const float4* zp0 = (const float4*)(yz + YZ_TOTAL + (size_t)cp.x * H_DIM);
        const float4* yp1 = (const float4*)(yz + (size_t)rp.y * H_DIM);
        const float4* zp1 = (const float4*)(yz + YZ_TOTAL + (size_t)cp.y * H_DIM);
        float4 y00 = yp0[0], y01 = yp0[1], z00 = zp0[0], z01 = zp0[1];
        float4 y10 = yp1[0], y11 = yp1[1], z10 = zp1[0], z11 = zp1[1];

        // index pass-through (paired NT stores)
        nt_store2(out + ib + e,     (float)rp.x, (float)rp.y);
        nt_store2(out + ib + E + e, (float)cp.x, (float)cp.y);

        float v0[8] = { y00.x + z00.x, y00.y + z00.y, y00.z + z00.z, y00.w + z00.w,
                        y01.x + z01.x, y01.y + z01.y, y01.z + z01.z, y01.w + z01.w };
        float v1[8] = { y10.x + z10.x, y10.y + z10.y, y10.z + z10.z, y10.w + z10.w,
                        y11.x + z11.x, y11.y + z11.y, y11.z + z11.z, y11.w + z11.w };
        const bool self0 = (rp.x == cp.x);
        const bool self1 = (rp.y == cp.y);
        float r0[8], r1[8];
#pragma unroll
        for (int h = 0; h < 8; ++h) {
            r0[h] = self0 ? 1.f : sigmoid_fast(v0[h]) * ap.x;
            r1[h] = self1 ? 1.f : sigmoid_fast(v1[h]) * ap.y;
        }
        nt_store4(out + (size_t)e * H_DIM,           r0[0], r0[1], r0[2], r0[3]);
        nt_store4(out + (size_t)e * H_DIM + 4,       r0[4], r0[5], r0[6], r0[7]);
        nt_store4(out + (size_t)(e + 1) * H_DIM,     r1[0], r1[1], r1[2], r1[3]);
        nt_store4(out + (size_t)(e + 1) * H_DIM + 4, r1[4], r1[5], r1[6], r1[7]);
    } else {
        // scalar tail (E odd; dead for E = 640000)
        int r = ei[e], c = ei[E + e];
        float a = ea[e];
        const float4* yp = (const float4*)(yz + (size_t)r * H_DIM);
        const float4* zp = (const float4*)(yz + YZ_TOTAL + (size_t)c * H_DIM);
        float4 y0 = yp[0], y1 = yp[1], z0 = zp[0], z1 = zp[1];
        float v[8] = { y0.x + z0.x, y0.y + z0.y, y0.z + z0.z, y0.w + z0.w,
                       y1.x + z1.x, y1.y + z1.y, y1.z + z1.z, y1.w + z1.w };
        bool self = (r == c);
        float res[8];
#pragma unroll
        for (int h = 0; h < 8; ++h)
            res[h] = self ? 1.f : sigmoid_fast(v[h]) * a;
        float4* op = (float4*)(out + (size_t)e * H_DIM);
        op[0] = make_float4(res[0], res[1], res[2], res[3]);
        op[1] = make_float4(res[4], res[5], res[6], res[7]);
        out[ib + e] = (float)r;
        out[ib + E + e] = (float)c;
    }
}

extern "C" void kernel_launch(void* const* d_in, const int* in_sizes, int n_in,
                              void* d_out, int out_size, void* d_ws, size_t ws_size,
                              hipStream_t stream) {
    const float* x  = (const float*)d_in[0];
    const int*   ei = (const int*)d_in[1];   // int32 on device per harness convention
    const float* ea = (const float*)d_in[2];
    const float* W  = (const float*)d_in[3];
    const float* b  = (const float*)d_in[4];
    float* out = (float*)d_out;
    float* yz  = (float*)d_ws;               // 2*N*H*4 = 640 KB
    const int E = in_sizes[2];               // 640000

    {
        const int total_threads = N_NODES * 32;                  // 320000
        const int grid = (total_threads + 255) / 256;            // 1250
        hipLaunchKernelGGL(precompute_yz, dim3(grid), dim3(256), 0, stream,
                           x, W, b, yz);
    }
    {
        const int threads = (E + 1) / 2;                         // 320000
        const int grid = (threads + 255) / 256;                  // 1250
        hipLaunchKernelGGL(edge_alpha, dim3(grid), dim3(256), 0, stream,
                           ei, ea, yz, out, E);
    }
}

// Round 8
// 23.610 us; speedup vs baseline: 9.5907x; 1.2469x over previous
//
#include <hip/hip_runtime.h>

#define N_NODES  10000
#define C_DIM    128
#define H_DIM    8
#define YZ_TOTAL (N_NODES * H_DIM)

// clang-native f16 vectors (single dwordx4 gather per node row)
typedef _Float16 h2 __attribute__((ext_vector_type(2)));
typedef _Float16 h8 __attribute__((ext_vector_type(8)));

// ---------------------------------------------------------------------------
// K1: R4 structure (32 thr/node, k-split butterfly), output packed f16.
// yzh layout: [0 .. YZ_TOTAL) = y rows (8 x f16 = 16B/node), then z rows.
// ---------------------------------------------------------------------------
__global__ void __launch_bounds__(256)
precompute_yz(const float* __restrict__ x, const float* __restrict__ W,
              const float* __restrict__ b, _Float16* __restrict__ yzh) {
    const int t = blockIdx.x * blockDim.x + threadIdx.x;
    const int n = t >> 5;
    if (n >= N_NODES) return;
    const int w  = t & 31;
    const int s  = w >> 2;
    const int hp = w & 3;
    const int h0 = hp * 2;

    const float4* xr4 = (const float4*)(x + (size_t)n * C_DIM) + s * 4;
    float4 xv0 = xr4[0], xv1 = xr4[1], xv2 = xr4[2], xv3 = xr4[3];
    const float xk[16] = { xv0.x,xv0.y,xv0.z,xv0.w, xv1.x,xv1.y,xv1.z,xv1.w,
                           xv2.x,xv2.y,xv2.z,xv2.w, xv3.x,xv3.y,xv3.z,xv3.w };

    const int k0 = s * 16;
    const float* wr = W + (size_t)k0 * H_DIM + h0;
    const float* wc = W + (size_t)(C_DIM + k0) * H_DIM + h0;

    float ar0 = 0.f, ar1 = 0.f, ac0 = 0.f, ac1 = 0.f;
#pragma unroll
    for (int j = 0; j < 16; ++j) {
        float2 wr2 = *(const float2*)(wr + j * H_DIM);
        float2 wc2 = *(const float2*)(wc + j * H_DIM);
        ar0 = fmaf(xk[j], wr2.x, ar0);
        ar1 = fmaf(xk[j], wr2.y, ar1);
        ac0 = fmaf(xk[j], wc2.x, ac0);
        ac1 = fmaf(xk[j], wc2.y, ac1);
    }
#pragma unroll
    for (int m = 4; m <= 16; m <<= 1) {
        ar0 += __shfl_xor(ar0, m, 64);
        ar1 += __shfl_xor(ar1, m, 64);
        ac0 += __shfl_xor(ac0, m, 64);
        ac1 += __shfl_xor(ac1, m, 64);
    }
    if (s == 0) {
        float2 bb = *(const float2*)(b + h0);
        h2 yv = { (_Float16)(ar0 + bb.x), (_Float16)(ar1 + bb.y) };
        h2 zv = { (_Float16)ac0,          (_Float16)ac1 };
        *(h2*)(yzh + (size_t)n * H_DIM + h0)            = yv;   // 4B store
        *(h2*)(yzh + YZ_TOTAL + (size_t)n * H_DIM + h0) = zv;   // 4B store
    }
}

// ---------------------------------------------------------------------------
// K2: R4 structure (1 thread/edge, 640k threads — keep full TLP).
// Gathers: ONE dwordx4 per y row + ONE per z row (was 2+2 with f32).
// ---------------------------------------------------------------------------
__device__ __forceinline__ float sigmoid_fast(float v) {
    return __builtin_amdgcn_rcpf(1.f + __expf(-v));   // absmax-safe (R1 precedent)
}

__global__ void edge_alpha(const int* __restrict__ ei,
                           const float* __restrict__ ea,
                           const _Float16* __restrict__ yzh,
                           float* __restrict__ out, int E) {
    const int e = blockIdx.x * blockDim.x + threadIdx.x;
    if (e >= E) return;
    int r = ei[e];
    int c = ei[E + e];
    float a = ea[e];

    h8 yv = *(const h8*)(yzh + (size_t)r * H_DIM);             // 16B gather
    h8 zv = *(const h8*)(yzh + YZ_TOTAL + (size_t)c * H_DIM);  // 16B gather

    const bool self = (r == c);
    float res[8];
#pragma unroll
    for (int h = 0; h < 8; ++h) {
        float v = (float)yv[h] + (float)zv[h];
        res[h] = self ? 1.f : sigmoid_fast(v) * a;
    }

    float4* op = (float4*)(out + (size_t)e * H_DIM);
    op[0] = make_float4(res[0], res[1], res[2], res[3]);
    op[1] = make_float4(res[4], res[5], res[6], res[7]);

    out[(size_t)E * H_DIM + e]     = (float)r;
    out[(size_t)E * H_DIM + E + e] = (float)c;
}

extern "C" void kernel_launch(void* const* d_in, const int* in_sizes, int n_in,
                              void* d_out, int out_size, void* d_ws, size_t ws_size,
                              hipStream_t stream) {
    const float* x  = (const float*)d_in[0];
    const int*   ei = (const int*)d_in[1];   // int32 on device per harness convention
    const float* ea = (const float*)d_in[2];
    const float* W  = (const float*)d_in[3];
    const float* b  = (const float*)d_in[4];
    float* out = (float*)d_out;
    _Float16* yzh = (_Float16*)d_ws;         // 2*N*H*2 = 320 KB
    const int E = in_sizes[2];               // 640000

    {
        const int total_threads = N_NODES * 32;                  // 320000
        const int grid = (total_threads + 255) / 256;            // 1250
        hipLaunchKernelGGL(precompute_yz, dim3(grid), dim3(256), 0, stream,
                           x, W, b, yzh);
    }
    {
        const int grid = (E + 255) / 256;                        // 2500
        hipLaunchKernelGGL(edge_alpha, dim3(grid), dim3(256), 0, stream,
                           ei, ea, yzh, out, E);
    }
}